// Round 3
// baseline (455.603 us; speedup 1.0000x reference)
//
#include <hip/hip_runtime.h>
#include <math.h>

#define B_    128
#define T_    24
#define NN    300
#define EE    9000
#define GG    (B_ * T_)
#define GRUH  12
#define OUTF  1200

// ---------------------------------------------------------------------------
// Kernel 0: pack src|dst<<16 into one uint per edge (topology shared by all
// graphs; halves index traffic and lets the main loop use uint4 loads).
// ---------------------------------------------------------------------------
__global__ __launch_bounds__(256) void pack_edges(
    const int* __restrict__ src, const int* __restrict__ dst,
    unsigned int* __restrict__ pk)
{
    int e = blockIdx.x * 256 + threadIdx.x;
    if (e < EE) pk[e] = (unsigned int)src[e] | ((unsigned int)dst[e] << 16);
}

// ---------------------------------------------------------------------------
// Kernel 1: per-graph EdgeGAT + mean pool, collapsed to scalar S[g].
//   logit_e = leakyrelu(cL*x[src] + cR*x[dst] + cE*ew[e])
//   S[g]    = sum_n num_n / den_n,  num/den accumulated via NATIVE LDS
//   float atomics (unsafeAtomicAdd -> ds_add_f32; plain atomicAdd on
//   __shared__ float is a CAS loop on gfx950 = round-2's 60x stall).
// 250 active threads x exactly 9 float4/uint4 packs, all 18 loads staged
// in registers up front for MLP.
// ---------------------------------------------------------------------------
__global__ __launch_bounds__(256) void gat_pool(
    const float* __restrict__ x, const float* __restrict__ ew,
    const unsigned int* __restrict__ pk,
    const float* __restrict__ w_node, const float* __restrict__ w_edge,
    const float* __restrict__ attn_l, const float* __restrict__ attn_r,
    const float* __restrict__ attn_e,
    float* __restrict__ S)
{
    __shared__ float xs[NN];
    __shared__ float den[NN];
    __shared__ float num[NN];
    __shared__ float red[4];

    const int g = blockIdx.x;
    const int tid = threadIdx.x;
    const bool active = tid < 250;   // 2250 packs = 9 * 250

    const float*  erow = ew + (size_t)g * EE;
    const float4* e4   = (const float4*)erow;
    const uint4*  p4   = (const uint4*)pk;

    // stage all 18 loads (coalesced, independent -> 18 outstanding per thread)
    float4 wv[9]; uint4 pki[9];
    if (active) {
#pragma unroll
        for (int i = 0; i < 9; i++) {
            int p = i * 250 + tid;
            wv[i]  = e4[p];
            pki[i] = p4[p];
        }
    }

    // scalar attention constants
    float cL = 0.f, cR = 0.f, cE = 0.f;
#pragma unroll
    for (int o = 0; o < 4; o++) {
        float wn = w_node[o];
        cL += wn * attn_l[o];
        cR += wn * attn_r[o];
        cE += w_edge[o] * attn_e[o];
    }

    const float* xrow = x + (size_t)g * NN;
    for (int i = tid; i < NN; i += 256) {
        xs[i]  = xrow[i];
        den[i] = 0.f;
        num[i] = 0.f;
    }
    __syncthreads();

    if (active) {
#pragma unroll
        for (int i = 0; i < 9; i++) {
#pragma unroll
            for (int k = 0; k < 4; k++) {
                unsigned int pv = (k == 0) ? pki[i].x : (k == 1) ? pki[i].y
                                : (k == 2) ? pki[i].z : pki[i].w;
                float wvv = (k == 0) ? wv[i].x : (k == 1) ? wv[i].y
                          : (k == 2) ? wv[i].z : wv[i].w;
                int si = (int)(pv & 0xFFFFu);
                int di = (int)(pv >> 16);
                float xsv = xs[si];
                float v = fmaf(cE, wvv, fmaf(cL, xsv, cR * xs[di]));
                v = fmaxf(v, 0.2f * v);          // leaky relu, branchless
                float ex = __expf(v);
                unsafeAtomicAdd(&den[di], ex);
                unsafeAtomicAdd(&num[di], ex * xsv);
            }
        }
    }
    __syncthreads();

    // per-node combine + block reduce
    float acc = 0.f;
    for (int n = tid; n < NN; n += 256) {
        float d = den[n];
        if (d > 0.f) acc += num[n] / d;
    }
    for (int off = 32; off > 0; off >>= 1) acc += __shfl_down(acc, off);
    if ((tid & 63) == 0) red[tid >> 6] = acc;
    __syncthreads();
    if (tid == 0) S[g] = red[0] + red[1] + red[2] + red[3];
}

// ---------------------------------------------------------------------------
// Kernel 2: GRU (24 steps, hidden 12) on wave 0 (no barriers: wave-lockstep
// LDS), then FC (12 -> 1200) with all 256 threads.
// pooled[b,t,o] = (S[g]/N) * w_node[o] + gat_bias[o]
// ---------------------------------------------------------------------------
__device__ __forceinline__ float sigmoidf_(float v) { return 1.0f / (1.0f + __expf(-v)); }

__global__ __launch_bounds__(256) void gru_fc(
    const float* __restrict__ S,
    const float* __restrict__ w_node, const float* __restrict__ gat_bias,
    const float* __restrict__ w_ih, const float* __restrict__ w_hh,
    const float* __restrict__ b_ih, const float* __restrict__ b_hh,
    const float* __restrict__ fc_w, const float* __restrict__ fc_b,
    float* __restrict__ out)
{
    __shared__ float Srow[T_];
    __shared__ float h[GRUH];
    __shared__ float gi_s[36], gh_s[36];

    const int b = blockIdx.x;
    const int tid = threadIdx.x;

    if (tid < T_) Srow[tid] = S[b * T_ + tid];
    if (tid < GRUH) h[tid] = 0.f;
    __syncthreads();

    if (tid < 64) {   // single wave runs the GRU; intra-wave LDS needs no barrier
        const int lane = tid;
        float wn[4], gb[4];
#pragma unroll
        for (int i = 0; i < 4; i++) {
            wn[i] = w_node[i] * (1.0f / (float)NN);
            gb[i] = gat_bias[i];
        }
        float wih[4], whh[12], bih = 0.f, bhh = 0.f;
        if (lane < 36) {
#pragma unroll
            for (int i = 0; i < 4; i++)  wih[i] = w_ih[lane * 4 + i];
#pragma unroll
            for (int j = 0; j < 12; j++) whh[j] = w_hh[lane * 12 + j];
            bih = b_ih[lane];
            bhh = b_hh[lane];
        }
        for (int t = 0; t < T_; t++) {
            const float Sg = Srow[t];
            if (lane < 36) {
                float gi = bih, gh = bhh;
#pragma unroll
                for (int i = 0; i < 4; i++)  gi += (Sg * wn[i] + gb[i]) * wih[i];
#pragma unroll
                for (int j = 0; j < 12; j++) gh += h[j] * whh[j];
                gi_s[lane] = gi;
                gh_s[lane] = gh;
            }
            if (lane < GRUH) {
                float r = sigmoidf_(gi_s[lane] + gh_s[lane]);
                float z = sigmoidf_(gi_s[12 + lane] + gh_s[12 + lane]);
                float n = tanhf(gi_s[24 + lane] + r * gh_s[24 + lane]);
                h[lane] = (1.f - z) * n + z * h[lane];
            }
        }
    }
    __syncthreads();

    // FC: h (12) x fc_w (1200x12), coalesced float4 weight rows
    float hr[GRUH];
#pragma unroll
    for (int k = 0; k < GRUH; k++) hr[k] = h[k];

    for (int j = tid; j < OUTF; j += 256) {
        const float4* wr = (const float4*)(fc_w + j * GRUH);
        float4 w0 = wr[0], w1 = wr[1], w2 = wr[2];
        float o = fc_b[j];
        o += hr[0] * w0.x + hr[1] * w0.y + hr[2]  * w0.z + hr[3]  * w0.w;
        o += hr[4] * w1.x + hr[5] * w1.y + hr[6]  * w1.z + hr[7]  * w1.w;
        o += hr[8] * w2.x + hr[9] * w2.y + hr[10] * w2.z + hr[11] * w2.w;
        out[(size_t)b * OUTF + j] = o;
    }
}

// ---------------------------------------------------------------------------
extern "C" void kernel_launch(void* const* d_in, const int* in_sizes, int n_in,
                              void* d_out, int out_size, void* d_ws, size_t ws_size,
                              hipStream_t stream)
{
    const float* x        = (const float*)d_in[0];
    const float* ew       = (const float*)d_in[1];
    const int*   src      = (const int*)d_in[2];
    const int*   dst      = (const int*)d_in[3];
    const float* w_node   = (const float*)d_in[4];
    const float* w_edge   = (const float*)d_in[5];
    const float* attn_l   = (const float*)d_in[6];
    const float* attn_r   = (const float*)d_in[7];
    const float* attn_e   = (const float*)d_in[8];
    const float* gat_bias = (const float*)d_in[9];
    const float* w_ih     = (const float*)d_in[10];
    const float* w_hh     = (const float*)d_in[11];
    const float* b_ih     = (const float*)d_in[12];
    const float* b_hh     = (const float*)d_in[13];
    const float* fc_w     = (const float*)d_in[14];
    const float* fc_b     = (const float*)d_in[15];
    float* out = (float*)d_out;

    // workspace layout: S[GG] floats, then pk[EE] uints (16B-aligned: 12288)
    float* S = (float*)d_ws;
    unsigned int* pk = (unsigned int*)((char*)d_ws + GG * sizeof(float));

    pack_edges<<<(EE + 255) / 256, 256, 0, stream>>>(src, dst, pk);
    gat_pool<<<GG, 256, 0, stream>>>(x, ew, pk, w_node, w_edge,
                                     attn_l, attn_r, attn_e, S);
    gru_fc<<<B_, 256, 0, stream>>>(S, w_node, gat_bias, w_ih, w_hh,
                                   b_ih, b_hh, fc_w, fc_b, out);
}